// Round 13
// baseline (109.456 us; speedup 1.0000x reference)
//
#include <hip/hip_runtime.h>
#include <math.h>

#define NWIRES 6
#define DIM 64
#define NTOK 32768            // B*T = 16*2048
#define NBATCH 16
#define TPB 2048              // tokens per batch
#define NMOM 16               // Taylor order: exp(az), |az|<=sqrt(6); rem ~8e-8
#define SQRT6F 2.4494897427831781f
#define APAD 76               // LDS row stride (ushorts), conflict-benign (R12)

typedef short bf16x8 __attribute__((ext_vector_type(8)));
typedef float f32x4  __attribute__((ext_vector_type(4)));

__device__ __forceinline__ unsigned f2bfbits(float f) {   // RNE fp32->bf16 bits
    unsigned u = __float_as_uint(f);
    return (u + 0x7FFF + ((u >> 16) & 1)) >> 16;
}
__device__ __forceinline__ float bfbits2f(unsigned b) {
    return __uint_as_float(b << 16);
}
__device__ __forceinline__ float pswap(float v) { return __shfl_xor(v, 1, 64); }

// ---------------------------------------------------------------------------
// Kernel 1: fused A-build + MFMA sim.  Grid (128, 3): 256-token tile, circuit.
//
// A-build (all 256 threads, redundant per block): A = [A_c; A_s],
// A_c = G*W*diag(cosd)*W (R10-12-verified math). Thread = (ph=tid>>7,
// k=(tid>>1)&63, h=tid&1): holds 32 floats = rows h*32+i of column k, phase ph
// (cos rows 0..63 / sin rows 64..127).  Lane-pair split (R5-verified pattern):
// wire0 (bit 32) ops go cross-lane via shfl_xor(.,1); wires 1..5 local.
// Writes bf16 hi/lo straight into LDS -- no global A, no separate kernel.
// R12 post-mortem: prepA (straight-line, 1 wave/block) + graph node was the
// last unmeasured ~6-10 us; this removes both.
//
// MFMA sim: R12's verified fragment layouts/epilogue; each wave does 4 chunks
// of 16 tokens (raw-X prefetch pipelined across chunks).
// ---------------------------------------------------------------------------
__global__ __launch_bounds__(256, 4) void qsa_sim(
        const float* __restrict__ x,
        const float* __restrict__ pq,
        const float* __restrict__ pk,
        const float* __restrict__ pv,
        float* __restrict__ zq,
        float* __restrict__ kv) {
    __shared__ unsigned short sAh[128 * APAD];   // 19456 B
    __shared__ unsigned short sAl[128 * APAD];   // 19456 B
    __shared__ float sTc[64], sTs[64], sP[24];
    int tid = threadIdx.x;
    int tbase = blockIdx.x * 256;
    int circ = blockIdx.y;
    const float* p = (circ == 0) ? pq : (circ == 1 ? pk : pv);

    // ---- issue chunk-0 X loads first (overlap with table+build compute) ----
    int lane = tid & 63, wv = tid >> 6;
    int q4 = lane >> 4, c16 = lane & 15;
    int mytok0 = wv * 64 + 0 * 16 + c16;
    const float* xr0 = x + ((size_t)(tbase + mytok0)) * 64;
    float4 rw[4];
#pragma unroll
    for (int ks = 0; ks < 2; ++ks) {
        rw[ks * 2 + 0] = *(const float4*)(xr0 + ks * 32 + q4 * 8);
        rw[ks * 2 + 1] = *(const float4*)(xr0 + ks * 32 + q4 * 8 + 4);
    }

    // ---- angle tables (threads 0..63) ----
    if (tid < 64) {
        int b = tid;
        float d = 0.f;
#pragma unroll
        for (int j = 0; j < 6; ++j)
            d += 0.5f * p[j] * ((b & (32 >> j)) ? -1.f : 1.f);
        float sd, cd;
        sincosf(d, &sd, &cd);
        sTc[b] = cd;
        sTs[b] = sd;
        if (b < 12) {                     // p[6..11]=RY0, p[12..17]=RY1
            float s, cc;
            sincosf(0.5f * p[6 + b], &s, &cc);
            sP[b * 2 + 0] = cc;
            sP[b * 2 + 1] = s;
        }
    }
    __syncthreads();

    // ---- A-build: thread (ph, k, h) evolves 32-float half-column ----
    {
        int ph = tid >> 7;                // 0: cos rows, 1: sin rows
        int k  = (tid >> 1) & 63;         // column
        int h  = tid & 1;                 // bit5 (value 32) of row index
        const float* sTx = ph ? sTs : sTc;
        float v[32];
#pragma unroll
        for (int i = 0; i < 32; ++i) {
            int g = h * 32 + i;
            v[i] = (__popc(g & k) & 1) ? -sTx[g] : sTx[g];   // diag(T) W e_k
        }
        // Walsh stage M=32 (split): lo'=lo+hi, hi'=lo-hi
#pragma unroll
        for (int i = 0; i < 32; ++i) {
            float pv_ = pswap(v[i]);
            v[i] = h ? (pv_ - v[i]) : (v[i] + pv_);
        }
        // Walsh stages M=16..1 (local)
#pragma unroll
        for (int M = 16; M >= 1; M >>= 1) {
#pragma unroll
            for (int i = 0; i < 32; ++i) {
                if (i & M) continue;
                int j = i | M;
                float a = v[i], b = v[j];
                v[i] = a + b; v[j] = a - b;
            }
        }
        // RY0 then CNOT ring then RY1
#pragma unroll
        for (int layer = 0; layer < 2; ++layer) {
            const float* Pl = sP + layer * 12;
            // wire0 (split): new = c*mine + (h? +s : -s)*partner
            {
                float c = Pl[0], ss = h ? Pl[1] : -Pl[1];
#pragma unroll
                for (int i = 0; i < 32; ++i) {
                    float pv_ = pswap(v[i]);
                    v[i] = c * v[i] + ss * pv_;
                }
            }
            // wires 1..5 local (masks 16,8,4,2,1)
#pragma unroll
            for (int w = 1; w < 6; ++w) {
                int M = 32 >> w;
                float c = Pl[w * 2], s = Pl[w * 2 + 1];
#pragma unroll
                for (int i = 0; i < 32; ++i) {
                    if (i & M) continue;
                    int j = i | M;
                    float a = v[i], b = v[j];
                    v[i] = c * a - s * b;
                    v[j] = s * a + c * b;
                }
            }
            if (layer == 0) {
                // CNOT(0,1): control bit32 (h), target 16 -> h=1 swaps i<->i|16
#pragma unroll
                for (int i = 0; i < 16; ++i) {
                    int j = i | 16;
                    float a = v[i], b = v[j];
                    v[i] = h ? b : a;
                    v[j] = h ? a : b;
                }
                // CNOT(1,2)(2,3)(3,4)(4,5): local renames
#pragma unroll
                for (int w = 1; w < 5; ++w) {
                    int MC = 32 >> w, MT = MC >> 1;
#pragma unroll
                    for (int i = 0; i < 32; ++i) {
                        if (!(i & MC) || (i & MT)) continue;
                        int j = i | MT;
                        float t = v[i]; v[i] = v[j]; v[j] = t;
                    }
                }
                // CNOT(5,0): control bit0, target bit32 -> odd i exchange lanes
#pragma unroll
                for (int i = 1; i < 32; i += 2) v[i] = pswap(v[i]);
            }
        }
        // pack bf16 hi/lo into LDS
#pragma unroll
        for (int i = 0; i < 32; ++i) {
            int row = ph * 64 + h * 32 + i;
            unsigned hb = f2bfbits(v[i]);
            unsigned lb = f2bfbits(v[i] - bfbits2f(hb));
            sAh[row * APAD + k] = (unsigned short)hb;
            sAl[row * APAD + k] = (unsigned short)lb;
        }
    }
    __syncthreads();

    // ---- MFMA chunks: wave wv handles tokens wv*64 + cg*16 + c16 ----
    bf16x8 xh[2], xl[2];
#pragma unroll 1
    for (int cg = 0; cg < 4; ++cg) {
        // convert current raws -> fragments
#pragma unroll
        for (int ks = 0; ks < 2; ++ks) {
            float4 f0 = rw[ks * 2], f1 = rw[ks * 2 + 1];
            float ff[8] = {f0.x, f0.y, f0.z, f0.w, f1.x, f1.y, f1.z, f1.w};
#pragma unroll
            for (int e = 0; e < 8; ++e) {
                unsigned hb = f2bfbits(ff[e]);
                unsigned lb = f2bfbits(ff[e] - bfbits2f(hb));
                xh[ks][e] = (short)hb;
                xl[ks][e] = (short)lb;
            }
        }
        int mytok = wv * 64 + cg * 16 + c16;
        // prefetch next chunk raws (overlaps MFMAs below)
        if (cg < 3) {
            const float* xrn = x + ((size_t)(tbase + mytok + 16)) * 64;
#pragma unroll
            for (int ks = 0; ks < 2; ++ks) {
                rw[ks * 2 + 0] = *(const float4*)(xrn + ks * 32 + q4 * 8);
                rw[ks * 2 + 1] = *(const float4*)(xrn + ks * 32 + q4 * 8 + 4);
            }
        }

        f32x4 acc[8];
#pragma unroll
        for (int mt = 0; mt < 8; ++mt) acc[mt] = (f32x4){0.f, 0.f, 0.f, 0.f};
#pragma unroll
        for (int mt = 0; mt < 8; ++mt) {
            int r = mt * 16 + c16;               // A-op row m
#pragma unroll
            for (int ks = 0; ks < 2; ++ks) {
                const uint2* ph_ = (const uint2*)(&sAh[r * APAD + ks * 32 + q4 * 8]);
                const uint2* pl_ = (const uint2*)(&sAl[r * APAD + ks * 32 + q4 * 8]);
                union { uint2 u[2]; bf16x8 v; } ua, ub;
                ua.u[0] = ph_[0]; ua.u[1] = ph_[1];
                ub.u[0] = pl_[0]; ub.u[1] = pl_[1];
                bf16x8 ah = ua.v, al = ub.v;
                acc[mt] = __builtin_amdgcn_mfma_f32_16x16x32_bf16(ah, xh[ks], acc[mt], 0, 0, 0);
                acc[mt] = __builtin_amdgcn_mfma_f32_16x16x32_bf16(ah, xl[ks], acc[mt], 0, 0, 0);
                acc[mt] = __builtin_amdgcn_mfma_f32_16x16x32_bf16(al, xh[ks], acc[mt], 0, 0, 0);
            }
        }

        // epilogue: p_r = dc^2 + ds^2, masked sums, 4-lane combine (R12-verified)
        float n = 0.f, s0 = 0.f, s1 = 0.f, s2 = 0.f, s3 = 0.f, s4 = 0.f, s5 = 0.f;
        float f2 = (q4 < 2) ? 1.f : 0.f;         // r bit3 == 0
        float f3 = (q4 & 1) ? 0.f : 1.f;         // r bit2 == 0
#pragma unroll
        for (int mt = 0; mt < 4; ++mt) {
#pragma unroll
            for (int rg = 0; rg < 4; ++rg) {
                float dc = acc[mt][rg];          // row r = mt*16 + q4*4 + rg
                float ds = acc[mt + 4][rg];      // row r + 64
                float pp = dc * dc + ds * ds;
                n += pp;
                if (!(mt & 2)) s0 += pp;         // bit5
                if (!(mt & 1)) s1 += pp;         // bit4
                s2 += f2 * pp;                   // bit3
                s3 += f3 * pp;                   // bit2
                if (!(rg & 2)) s4 += pp;         // bit1
                if (!(rg & 1)) s5 += pp;         // bit0
            }
        }
#pragma unroll
        for (int d = 16; d <= 32; d <<= 1) {
            n  += __shfl_xor(n,  d, 64);
            s0 += __shfl_xor(s0, d, 64);
            s1 += __shfl_xor(s1, d, 64);
            s2 += __shfl_xor(s2, d, 64);
            s3 += __shfl_xor(s3, d, 64);
            s4 += __shfl_xor(s4, d, 64);
            s5 += __shfl_xor(s5, d, 64);
        }
        if (q4 == 0) {
            int t = tbase + mytok;
            float inv = 1.0f / n;
            if (circ == 0) {
                zq[t] = SQRT6F * (2.f * s0 - n) * inv;   // a_t, natural-exp scale
            } else if (circ == 1) {
                kv[(size_t)t * 8] = (2.f * s0 - n) * inv;
            } else {
                float* o = kv + (size_t)t * 8;
                o[1] = (2.f*s0 - n) * inv;
                o[2] = (2.f*s1 - n) * inv;
                o[3] = (2.f*s2 - n) * inv;
                o[4] = (2.f*s3 - n) * inv;
                o[5] = (2.f*s4 - n) * inv;
                o[6] = (2.f*s5 - n) * inv;
                o[7] = 0.f;
            }
        }
    }
}

// ---------------------------------------------------------------------------
// Kernel 2: partial power moments per (batch, chunk-of-256).
// S_m = sum z^m, H_{m,w} = sum z^m * v_w, m=0..15.  Butterfly wave-reduce.
// ---------------------------------------------------------------------------
__global__ __attribute__((amdgpu_waves_per_eu(1, 2)))
__launch_bounds__(64) void qsa_moments_partial(
        const float* __restrict__ kv,
        float* __restrict__ mpart) {
    int blk = blockIdx.x;             // 16 batches * 8 chunks
    int b = blk >> 3, c = blk & 7;
    int lane = threadIdx.x;
    float S[NMOM], H[NMOM][6];
#pragma unroll
    for (int m = 0; m < NMOM; ++m) {
        S[m] = 0.f;
#pragma unroll
        for (int w = 0; w < 6; ++w) H[m][w] = 0.f;
    }
    const float* base = kv + ((size_t)(b * TPB + c * 256)) * 8;
#pragma unroll
    for (int r = 0; r < 4; ++r) {
        const float4* e = (const float4*)(base + (size_t)(r * 64 + lane) * 8);
        float4 e0 = e[0], e1 = e[1];
        float z = e0.x;
        float v0 = e0.y, v1 = e0.z, v2 = e0.w, v3 = e1.x, v4 = e1.y, v5 = e1.z;
        float pw = 1.f;
#pragma unroll
        for (int m = 0; m < NMOM; ++m) {
            S[m] += pw;
            H[m][0] += pw * v0; H[m][1] += pw * v1; H[m][2] += pw * v2;
            H[m][3] += pw * v3; H[m][4] += pw * v4; H[m][5] += pw * v5;
            pw *= z;
        }
    }
#pragma unroll
    for (int d = 32; d >= 1; d >>= 1) {
#pragma unroll
        for (int m = 0; m < NMOM; ++m) {
            S[m] += __shfl_xor(S[m], d, 64);
#pragma unroll
            for (int w = 0; w < 6; ++w) H[m][w] += __shfl_xor(H[m][w], d, 64);
        }
    }
    if (lane == 0) {
        float* o = mpart + (size_t)blk * 112;
#pragma unroll
        for (int m = 0; m < NMOM; ++m) {
            float* om = o + m * 7;
            om[0] = S[m];
            om[1] = H[m][0]; om[2] = H[m][1]; om[3] = H[m][2];
            om[4] = H[m][3]; om[5] = H[m][4]; om[6] = H[m][5];
        }
    }
}

// ---------------------------------------------------------------------------
// Kernel 3: fused combine + per-token evaluation (one block = 256 tokens).
// den = sum_m p_m S_m, out_w = sum_m p_m H_mw, p_m = a^m/m!.
// ---------------------------------------------------------------------------
__global__ __launch_bounds__(256) void qsa_eval(
        const float* __restrict__ zq,
        const float* __restrict__ mpart,
        float* __restrict__ out) {
    __shared__ float sm[112];
    int bk = blockIdx.x;                      // 128 blocks
    int b = bk >> 3;                          // 8 blocks per batch
    int tid = threadIdx.x;
    if (tid < 112) {
        float s = 0.f;
#pragma unroll
        for (int c = 0; c < 8; ++c) s += mpart[(size_t)(b * 8 + c) * 112 + tid];
        sm[tid] = s;
    }
    __syncthreads();

    int t = bk * 256 + tid;
    float a = zq[t];
    float den = 0.f, o0 = 0.f, o1 = 0.f, o2 = 0.f, o3 = 0.f, o4 = 0.f, o5 = 0.f;
    float pw = 1.f;
#pragma unroll
    for (int m = 0; m < NMOM; ++m) {
        const float* mm = sm + m * 7;
        den += pw * mm[0];
        o0 += pw * mm[1]; o1 += pw * mm[2]; o2 += pw * mm[3];
        o3 += pw * mm[4]; o4 += pw * mm[5]; o5 += pw * mm[6];
        pw *= a * (1.0f / (m + 1));           // p_{m+1} = p_m * a/(m+1)
    }
    float inv = 1.0f / den;
    float* o = out + (size_t)t * 6;
    float2* o2p = (float2*)o;                 // t*24B is 8-aligned
    o2p[0] = make_float2(o0 * inv, o1 * inv);
    o2p[1] = make_float2(o2 * inv, o3 * inv);
    o2p[2] = make_float2(o4 * inv, o5 * inv);
}

// ---------------------------------------------------------------------------
extern "C" void kernel_launch(void* const* d_in, const int* in_sizes, int n_in,
                              void* d_out, int out_size, void* d_ws, size_t ws_size,
                              hipStream_t stream) {
    const float* x  = (const float*)d_in[0];
    const float* pq = (const float*)d_in[1];
    const float* pk = (const float*)d_in[2];
    const float* pv = (const float*)d_in[3];
    float* w = (float*)d_ws;
    // ws (floats): zq[32768] | kv[262144] | mpart[14336]
    float* zq    = w;
    float* kv    = zq + NTOK;
    float* mpart = kv + NTOK * 8;
    float* out   = (float*)d_out;

    qsa_sim<<<dim3(NTOK / 256, 3), 256, 0, stream>>>(x, pq, pk, pv, zq, kv);
    qsa_moments_partial<<<NBATCH * 8, 64, 0, stream>>>(kv, mpart);
    qsa_eval<<<NTOK / 256, 256, 0, stream>>>(zq, mpart, out);
}

// Round 14
// 85.436 us; speedup vs baseline: 1.2811x; 1.2811x over previous
//
#include <hip/hip_runtime.h>
#include <math.h>

#define NWIRES 6
#define DIM 64
#define NTOK 32768            // B*T = 16*2048
#define NBATCH 16
#define TPB 2048              // tokens per batch
#define NMOM 16               // Taylor order: exp(az), |az|<=sqrt(6); rem ~8e-8
#define SQRT6F 2.4494897427831781f
#define APAD 76               // LDS row stride (ushorts), conflict-benign (R12)

typedef short bf16x8 __attribute__((ext_vector_type(8)));
typedef float f32x4  __attribute__((ext_vector_type(4)));

__device__ __forceinline__ unsigned f2bfbits(float f) {   // RNE fp32->bf16 bits
    unsigned u = __float_as_uint(f);
    return (u + 0x7FFF + ((u >> 16) & 1)) >> 16;
}
__device__ __forceinline__ float bfbits2f(unsigned b) {
    return __uint_as_float(b << 16);
}
__device__ __forceinline__ float pswap(float v) { return __shfl_xor(v, 1, 64); }

// ---------------------------------------------------------------------------
// Kernel 1: fused A-build + MFMA sim.  Grid (128, 3): 256-token tile, circuit.
// Identical to R13 except the occupancy attribute:
// R13 post-mortem: __launch_bounds__(256,4) -> allocator picked 64 VGPR and
// spilled 31 MB (WRITE_SIZE 32.8 MB, MfmaUtil 3.8%).  waves_per_eu(1,4) is
// the one config measured to allocate what's live under a 128 cap with zero
// spill (R9: VGPR=88).  Live set here ~80.  Max 4 waves/EU == the LDS limit
// (39 KB/block -> 4 blocks/CU), so the cap costs no occupancy.
// ---------------------------------------------------------------------------
__global__ __attribute__((amdgpu_waves_per_eu(1, 4)))
__launch_bounds__(256) void qsa_sim(
        const float* __restrict__ x,
        const float* __restrict__ pq,
        const float* __restrict__ pk,
        const float* __restrict__ pv,
        float* __restrict__ zq,
        float* __restrict__ kv) {
    __shared__ unsigned short sAh[128 * APAD];   // 19456 B
    __shared__ unsigned short sAl[128 * APAD];   // 19456 B
    __shared__ float sTc[64], sTs[64], sP[24];
    int tid = threadIdx.x;
    int tbase = blockIdx.x * 256;
    int circ = blockIdx.y;
    const float* p = (circ == 0) ? pq : (circ == 1 ? pk : pv);

    // ---- issue chunk-0 X loads first (overlap with table+build compute) ----
    int lane = tid & 63, wv = tid >> 6;
    int q4 = lane >> 4, c16 = lane & 15;
    int mytok0 = wv * 64 + 0 * 16 + c16;
    const float* xr0 = x + ((size_t)(tbase + mytok0)) * 64;
    float4 rw[4];
#pragma unroll
    for (int ks = 0; ks < 2; ++ks) {
        rw[ks * 2 + 0] = *(const float4*)(xr0 + ks * 32 + q4 * 8);
        rw[ks * 2 + 1] = *(const float4*)(xr0 + ks * 32 + q4 * 8 + 4);
    }

    // ---- angle tables (threads 0..63) ----
    if (tid < 64) {
        int b = tid;
        float d = 0.f;
#pragma unroll
        for (int j = 0; j < 6; ++j)
            d += 0.5f * p[j] * ((b & (32 >> j)) ? -1.f : 1.f);
        float sd, cd;
        sincosf(d, &sd, &cd);
        sTc[b] = cd;
        sTs[b] = sd;
        if (b < 12) {                     // p[6..11]=RY0, p[12..17]=RY1
            float s, cc;
            sincosf(0.5f * p[6 + b], &s, &cc);
            sP[b * 2 + 0] = cc;
            sP[b * 2 + 1] = s;
        }
    }
    __syncthreads();

    // ---- A-build: thread (ph, k, h) evolves 32-float half-column ----
    {
        int ph = tid >> 7;                // 0: cos rows, 1: sin rows
        int k  = (tid >> 1) & 63;         // column
        int h  = tid & 1;                 // bit5 (value 32) of row index
        const float* sTx = ph ? sTs : sTc;
        float v[32];
#pragma unroll
        for (int i = 0; i < 32; ++i) {
            int g = h * 32 + i;
            v[i] = (__popc(g & k) & 1) ? -sTx[g] : sTx[g];   // diag(T) W e_k
        }
        // Walsh stage M=32 (split): lo'=lo+hi, hi'=lo-hi
#pragma unroll
        for (int i = 0; i < 32; ++i) {
            float pv_ = pswap(v[i]);
            v[i] = h ? (pv_ - v[i]) : (v[i] + pv_);
        }
        // Walsh stages M=16..1 (local)
#pragma unroll
        for (int M = 16; M >= 1; M >>= 1) {
#pragma unroll
            for (int i = 0; i < 32; ++i) {
                if (i & M) continue;
                int j = i | M;
                float a = v[i], b = v[j];
                v[i] = a + b; v[j] = a - b;
            }
        }
        // RY0 then CNOT ring then RY1
#pragma unroll
        for (int layer = 0; layer < 2; ++layer) {
            const float* Pl = sP + layer * 12;
            // wire0 (split): new = c*mine + (h? +s : -s)*partner
            {
                float c = Pl[0], ss = h ? Pl[1] : -Pl[1];
#pragma unroll
                for (int i = 0; i < 32; ++i) {
                    float pv_ = pswap(v[i]);
                    v[i] = c * v[i] + ss * pv_;
                }
            }
            // wires 1..5 local (masks 16,8,4,2,1)
#pragma unroll
            for (int w = 1; w < 6; ++w) {
                int M = 32 >> w;
                float c = Pl[w * 2], s = Pl[w * 2 + 1];
#pragma unroll
                for (int i = 0; i < 32; ++i) {
                    if (i & M) continue;
                    int j = i | M;
                    float a = v[i], b = v[j];
                    v[i] = c * a - s * b;
                    v[j] = s * a + c * b;
                }
            }
            if (layer == 0) {
                // CNOT(0,1): control bit32 (h), target 16 -> h=1 swaps i<->i|16
#pragma unroll
                for (int i = 0; i < 16; ++i) {
                    int j = i | 16;
                    float a = v[i], b = v[j];
                    v[i] = h ? b : a;
                    v[j] = h ? a : b;
                }
                // CNOT(1,2)(2,3)(3,4)(4,5): local renames
#pragma unroll
                for (int w = 1; w < 5; ++w) {
                    int MC = 32 >> w, MT = MC >> 1;
#pragma unroll
                    for (int i = 0; i < 32; ++i) {
                        if (!(i & MC) || (i & MT)) continue;
                        int j = i | MT;
                        float t = v[i]; v[i] = v[j]; v[j] = t;
                    }
                }
                // CNOT(5,0): control bit0, target bit32 -> odd i exchange lanes
#pragma unroll
                for (int i = 1; i < 32; i += 2) v[i] = pswap(v[i]);
            }
        }
        // pack bf16 hi/lo into LDS
#pragma unroll
        for (int i = 0; i < 32; ++i) {
            int row = ph * 64 + h * 32 + i;
            unsigned hb = f2bfbits(v[i]);
            unsigned lb = f2bfbits(v[i] - bfbits2f(hb));
            sAh[row * APAD + k] = (unsigned short)hb;
            sAl[row * APAD + k] = (unsigned short)lb;
        }
    }
    __syncthreads();

    // ---- MFMA chunks: wave wv handles tokens wv*64 + cg*16 + c16 ----
    bf16x8 xh[2], xl[2];
#pragma unroll 1
    for (int cg = 0; cg < 4; ++cg) {
        // convert current raws -> fragments
#pragma unroll
        for (int ks = 0; ks < 2; ++ks) {
            float4 f0 = rw[ks * 2], f1 = rw[ks * 2 + 1];
            float ff[8] = {f0.x, f0.y, f0.z, f0.w, f1.x, f1.y, f1.z, f1.w};
#pragma unroll
            for (int e = 0; e < 8; ++e) {
                unsigned hb = f2bfbits(ff[e]);
                unsigned lb = f2bfbits(ff[e] - bfbits2f(hb));
                xh[ks][e] = (short)hb;
                xl[ks][e] = (short)lb;
            }
        }
        int mytok = wv * 64 + cg * 16 + c16;
        // prefetch next chunk raws (overlaps MFMAs below)
        if (cg < 3) {
            const float* xrn = x + ((size_t)(tbase + mytok + 16)) * 64;
#pragma unroll
            for (int ks = 0; ks < 2; ++ks) {
                rw[ks * 2 + 0] = *(const float4*)(xrn + ks * 32 + q4 * 8);
                rw[ks * 2 + 1] = *(const float4*)(xrn + ks * 32 + q4 * 8 + 4);
            }
        }

        f32x4 acc[8];
#pragma unroll
        for (int mt = 0; mt < 8; ++mt) acc[mt] = (f32x4){0.f, 0.f, 0.f, 0.f};
#pragma unroll
        for (int mt = 0; mt < 8; ++mt) {
            int r = mt * 16 + c16;               // A-op row m
#pragma unroll
            for (int ks = 0; ks < 2; ++ks) {
                const uint2* ph_ = (const uint2*)(&sAh[r * APAD + ks * 32 + q4 * 8]);
                const uint2* pl_ = (const uint2*)(&sAl[r * APAD + ks * 32 + q4 * 8]);
                union { uint2 u[2]; bf16x8 v; } ua, ub;
                ua.u[0] = ph_[0]; ua.u[1] = ph_[1];
                ub.u[0] = pl_[0]; ub.u[1] = pl_[1];
                bf16x8 ah = ua.v, al = ub.v;
                acc[mt] = __builtin_amdgcn_mfma_f32_16x16x32_bf16(ah, xh[ks], acc[mt], 0, 0, 0);
                acc[mt] = __builtin_amdgcn_mfma_f32_16x16x32_bf16(ah, xl[ks], acc[mt], 0, 0, 0);
                acc[mt] = __builtin_amdgcn_mfma_f32_16x16x32_bf16(al, xh[ks], acc[mt], 0, 0, 0);
            }
        }

        // epilogue: p_r = dc^2 + ds^2, masked sums, 4-lane combine (R12-verified)
        float n = 0.f, s0 = 0.f, s1 = 0.f, s2 = 0.f, s3 = 0.f, s4 = 0.f, s5 = 0.f;
        float f2 = (q4 < 2) ? 1.f : 0.f;         // r bit3 == 0
        float f3 = (q4 & 1) ? 0.f : 1.f;         // r bit2 == 0
#pragma unroll
        for (int mt = 0; mt < 4; ++mt) {
#pragma unroll
            for (int rg = 0; rg < 4; ++rg) {
                float dc = acc[mt][rg];          // row r = mt*16 + q4*4 + rg
                float ds = acc[mt + 4][rg];      // row r + 64
                float pp = dc * dc + ds * ds;
                n += pp;
                if (!(mt & 2)) s0 += pp;         // bit5
                if (!(mt & 1)) s1 += pp;         // bit4
                s2 += f2 * pp;                   // bit3
                s3 += f3 * pp;                   // bit2
                if (!(rg & 2)) s4 += pp;         // bit1
                if (!(rg & 1)) s5 += pp;         // bit0
            }
        }
#pragma unroll
        for (int d = 16; d <= 32; d <<= 1) {
            n  += __shfl_xor(n,  d, 64);
            s0 += __shfl_xor(s0, d, 64);
            s1 += __shfl_xor(s1, d, 64);
            s2 += __shfl_xor(s2, d, 64);
            s3 += __shfl_xor(s3, d, 64);
            s4 += __shfl_xor(s4, d, 64);
            s5 += __shfl_xor(s5, d, 64);
        }
        if (q4 == 0) {
            int t = tbase + mytok;
            float inv = 1.0f / n;
            if (circ == 0) {
                zq[t] = SQRT6F * (2.f * s0 - n) * inv;   // a_t, natural-exp scale
            } else if (circ == 1) {
                kv[(size_t)t * 8] = (2.f * s0 - n) * inv;
            } else {
                float* o = kv + (size_t)t * 8;
                o[1] = (2.f*s0 - n) * inv;
                o[2] = (2.f*s1 - n) * inv;
                o[3] = (2.f*s2 - n) * inv;
                o[4] = (2.f*s3 - n) * inv;
                o[5] = (2.f*s4 - n) * inv;
                o[6] = (2.f*s5 - n) * inv;
                o[7] = 0.f;
            }
        }
    }
}

// ---------------------------------------------------------------------------
// Kernel 2: partial power moments per (batch, chunk-of-256).
// S_m = sum z^m, H_{m,w} = sum z^m * v_w, m=0..15.  Butterfly wave-reduce.
// ---------------------------------------------------------------------------
__global__ __attribute__((amdgpu_waves_per_eu(1, 2)))
__launch_bounds__(64) void qsa_moments_partial(
        const float* __restrict__ kv,
        float* __restrict__ mpart) {
    int blk = blockIdx.x;             // 16 batches * 8 chunks
    int b = blk >> 3, c = blk & 7;
    int lane = threadIdx.x;
    float S[NMOM], H[NMOM][6];
#pragma unroll
    for (int m = 0; m < NMOM; ++m) {
        S[m] = 0.f;
#pragma unroll
        for (int w = 0; w < 6; ++w) H[m][w] = 0.f;
    }
    const float* base = kv + ((size_t)(b * TPB + c * 256)) * 8;
#pragma unroll
    for (int r = 0; r < 4; ++r) {
        const float4* e = (const float4*)(base + (size_t)(r * 64 + lane) * 8);
        float4 e0 = e[0], e1 = e[1];
        float z = e0.x;
        float v0 = e0.y, v1 = e0.z, v2 = e0.w, v3 = e1.x, v4 = e1.y, v5 = e1.z;
        float pw = 1.f;
#pragma unroll
        for (int m = 0; m < NMOM; ++m) {
            S[m] += pw;
            H[m][0] += pw * v0; H[m][1] += pw * v1; H[m][2] += pw * v2;
            H[m][3] += pw * v3; H[m][4] += pw * v4; H[m][5] += pw * v5;
            pw *= z;
        }
    }
#pragma unroll
    for (int d = 32; d >= 1; d >>= 1) {
#pragma unroll
        for (int m = 0; m < NMOM; ++m) {
            S[m] += __shfl_xor(S[m], d, 64);
#pragma unroll
            for (int w = 0; w < 6; ++w) H[m][w] += __shfl_xor(H[m][w], d, 64);
        }
    }
    if (lane == 0) {
        float* o = mpart + (size_t)blk * 112;
#pragma unroll
        for (int m = 0; m < NMOM; ++m) {
            float* om = o + m * 7;
            om[0] = S[m];
            om[1] = H[m][0]; om[2] = H[m][1]; om[3] = H[m][2];
            om[4] = H[m][3]; om[5] = H[m][4]; om[6] = H[m][5];
        }
    }
}

// ---------------------------------------------------------------------------
// Kernel 3: fused combine + per-token evaluation (one block = 256 tokens).
// den = sum_m p_m S_m, out_w = sum_m p_m H_mw, p_m = a^m/m!.
// ---------------------------------------------------------------------------
__global__ __launch_bounds__(256) void qsa_eval(
        const float* __restrict__ zq,
        const float* __restrict__ mpart,
        float* __restrict__ out) {
    __shared__ float sm[112];
    int bk = blockIdx.x;                      // 128 blocks
    int b = bk >> 3;                          // 8 blocks per batch
    int tid = threadIdx.x;
    if (tid < 112) {
        float s = 0.f;
#pragma unroll
        for (int c = 0; c < 8; ++c) s += mpart[(size_t)(b * 8 + c) * 112 + tid];
        sm[tid] = s;
    }
    __syncthreads();

    int t = bk * 256 + tid;
    float a = zq[t];
    float den = 0.f, o0 = 0.f, o1 = 0.f, o2 = 0.f, o3 = 0.f, o4 = 0.f, o5 = 0.f;
    float pw = 1.f;
#pragma unroll
    for (int m = 0; m < NMOM; ++m) {
        const float* mm = sm + m * 7;
        den += pw * mm[0];
        o0 += pw * mm[1]; o1 += pw * mm[2]; o2 += pw * mm[3];
        o3 += pw * mm[4]; o4 += pw * mm[5]; o5 += pw * mm[6];
        pw *= a * (1.0f / (m + 1));           // p_{m+1} = p_m * a/(m+1)
    }
    float inv = 1.0f / den;
    float* o = out + (size_t)t * 6;
    float2* o2p = (float2*)o;                 // t*24B is 8-aligned
    o2p[0] = make_float2(o0 * inv, o1 * inv);
    o2p[1] = make_float2(o2 * inv, o3 * inv);
    o2p[2] = make_float2(o4 * inv, o5 * inv);
}

// ---------------------------------------------------------------------------
extern "C" void kernel_launch(void* const* d_in, const int* in_sizes, int n_in,
                              void* d_out, int out_size, void* d_ws, size_t ws_size,
                              hipStream_t stream) {
    const float* x  = (const float*)d_in[0];
    const float* pq = (const float*)d_in[1];
    const float* pk = (const float*)d_in[2];
    const float* pv = (const float*)d_in[3];
    float* w = (float*)d_ws;
    // ws (floats): zq[32768] | kv[262144] | mpart[14336]
    float* zq    = w;
    float* kv    = zq + NTOK;
    float* mpart = kv + NTOK * 8;
    float* out   = (float*)d_out;

    qsa_sim<<<dim3(NTOK / 256, 3), 256, 0, stream>>>(x, pq, pk, pv, zq, kv);
    qsa_moments_partial<<<NBATCH * 8, 64, 0, stream>>>(kv, mpart);
    qsa_eval<<<NTOK / 256, 256, 0, stream>>>(zq, mpart, out);
}